// Round 1
// baseline (389.163 us; speedup 1.0000x reference)
//
#include <hip/hip_runtime.h>
#include <stdint.h>

#define DIM 512
#define ROWS_PER_BLOCK 16                // one wave, 16 rows
#define N_CHUNKS 32                      // 32 chunks of 16 e-columns
#define CHUNK_BYTES 8192                 // 16 rows x 512 fp8 (atom-rotated, no pad)
#define WS_BYTES (N_CHUNKS * CHUNK_BYTES)   // 262144

typedef __attribute__((ext_vector_type(4))) float f32x4;
typedef __attribute__((ext_vector_type(2))) float f32x2;
typedef __attribute__((ext_vector_type(4))) int   i32x4;

// k-permutation (validated rounds 1-3): position q = g*8+j within 32-k block kk
// holds k = 32*kk + (j<4 ? 4g+j : 16+4g+(j-4)). Any A/B-consistent bijection is
// mathematically valid; this one puts epilogue value delta[r][e] in-lane:
// e = 16*eb + 4g + i  <->  frag[eb>>1], byte (eb&1)*4 + i.
static __device__ __forceinline__ int kperm(int kk, int q) {
  int g = q >> 3, j = q & 7;
  int r = (j < 4) ? (g * 4 + j) : (16 + g * 4 + (j - 4));
  return kk * 32 + r;
}

// Build fp8 image of 64*(S - I), pre-swizzled: chunk -> 16 rows (e_l) x 512 B.
// Within a row, 16B atom (P,g) [atom index 4P+g] is stored at physical slot
// ((4P+g)+e_l)&31. (Rotation was for LDS banks; harmless for L2 reads, and the
// layout is validated — kept byte-identical.)
__global__ void prep_R(const float* __restrict__ S, uint32_t* __restrict__ ws) {
  int idx = blockIdx.x * blockDim.x + threadIdx.x;   // word index
  if (idx >= WS_BYTES / 4) return;
  int b     = idx * 4;
  int chunk = b >> 13;
  int e_l   = (b >> 9) & 15;
  int inrow = b & 511;
  int slot  = inrow >> 4;
  int bia   = inrow & 15;                // byte-in-atom base (0,4,8,12)
  int la    = (slot - e_l) & 31;         // logical atom = 4P+g
  int P = la >> 2, g = la & 3;
  int e = chunk * 16 + e_l;
  float v[4];
#pragma unroll
  for (int t = 0; t < 4; ++t) {
    int bb = bia + t;                    // byte in atom 0..15
    int j  = bb & 7;
    int kk = 2 * P + (bb >> 3);
    int k  = kperm(kk, g * 8 + j);
    v[t] = 64.0f * (S[k * DIM + e] - (k == e ? 1.0f : 0.0f));   // x64: e4m3 range
  }
  int w = __builtin_amdgcn_cvt_pk_fp8_f32(v[0], v[1], 0, false);
  w     = __builtin_amdgcn_cvt_pk_fp8_f32(v[2], v[3], w, true);
  ws[idx] = (uint32_t)w;
}

// ---- Phase 0 (template-unrolled, constant frag indices) ----
template <int KK>
struct P0 {
  static __device__ __forceinline__ void run(const float* __restrict__ xr,
                                             const float* __restrict__ fr,
                                             int g, long long (&fragL)[16], float& sumsq) {
    const float4 a0 = *(const float4*)(xr + KK * 32 + 4 * g);
    const float4 b0 = *(const float4*)(fr + KK * 32 + 4 * g);
    const float4 a1 = *(const float4*)(xr + KK * 32 + 16 + 4 * g);
    const float4 b1 = *(const float4*)(fr + KK * 32 + 16 + 4 * g);
    float d0 = a0.x - b0.x, d1 = a0.y - b0.y, d2 = a0.z - b0.z, d3 = a0.w - b0.w;
    float d4 = a1.x - b1.x, d5 = a1.y - b1.y, d6 = a1.z - b1.z, d7 = a1.w - b1.w;
    sumsq += d0*d0 + d1*d1 + d2*d2 + d3*d3 + d4*d4 + d5*d5 + d6*d6 + d7*d7;
    int lo = __builtin_amdgcn_cvt_pk_fp8_f32(d0, d1, 0, false);
    lo     = __builtin_amdgcn_cvt_pk_fp8_f32(d2, d3, lo, true);
    int hi = __builtin_amdgcn_cvt_pk_fp8_f32(d4, d5, 0, false);
    hi     = __builtin_amdgcn_cvt_pk_fp8_f32(d6, d7, hi, true);
    fragL[KK] = (long long)(((unsigned long long)(unsigned)hi << 32) | (unsigned)lo);
    P0<KK + 1>::run(xr, fr, g, fragL, sumsq);
  }
};
template <>
struct P0<16> {
  static __device__ __forceinline__ void run(const float*, const float*, int,
                                             long long (&)[16], float&) {}
};

// ---- Load one chunk's 8 A-atoms (16B each) straight from L2 into registers.
// Lane (m,g) reads chunk_base + m*512 + ((4P+g+m)&31)*16 — identical bytes to
// the old LDS image. Per instruction: 16 rows x 64B contiguous segments. ----
template <int P>
struct ALoad {
  static __device__ __forceinline__ void run(const char* __restrict__ cbase,
                                             int rot, i32x4 (&A)[8]) {
    int off = ((4 * P + rot) & 31) * 16;   // rotated atom slot
    A[P] = *(const i32x4*)(cbase + off);
    ALoad<P + 1>::run(cbase, rot, A);
  }
};
template <>
struct ALoad<8> {
  static __device__ __forceinline__ void run(const char*, int, i32x4 (&)[8]) {}
};

// ---- 8 atom-steps; each 16B register pair feeds two fp8 MFMAs ----
template <int P>
struct AMfma {
  static __device__ __forceinline__ void run(const i32x4 (&A)[8],
                                             const long long (&fragL)[16],
                                             f32x4& c0, f32x4& c1) {
    long long A0 = (long long)(((unsigned long long)(unsigned)A[P][1] << 32) | (unsigned)A[P][0]);
    long long A1 = (long long)(((unsigned long long)(unsigned)A[P][3] << 32) | (unsigned)A[P][2]);
    c0 = __builtin_amdgcn_mfma_f32_16x16x32_fp8_fp8(A0, fragL[2 * P],     c0, 0, 0, 0);
    c1 = __builtin_amdgcn_mfma_f32_16x16x32_fp8_fp8(A1, fragL[2 * P + 1], c1, 0, 0, 0);
    AMfma<P + 1>::run(A, fragL, c0, c1);
  }
};
template <>
struct AMfma<8> {
  static __device__ __forceinline__ void run(const i32x4 (&)[8],
                                             const long long (&)[16], f32x4&, f32x4&) {}
};

// ---- Chunk loop: register double-buffer, one chunk prefetched ahead.
// No LDS, no barriers — compiler emits counted vmcnt waits (8 loads of the
// next chunk stay in flight across each chunk's 16 MFMAs). cur/nxt swap via
// argument order, so every array index is compile-time (no scratch). ----
template <int EB>
struct ChunkLoop {
  static __device__ __forceinline__ void run(const char* __restrict__ wsb,
                                             int rot,
                                             const long long (&fragL)[16],
                                             i32x4 (&cur)[8], i32x4 (&nxt)[8],
                                             float& part) {
    if constexpr (EB + 1 < N_CHUNKS)
      ALoad<0>::run(wsb + (size_t)(EB + 1) * CHUNK_BYTES, rot, nxt);

    f32x4 c0 = {0.f, 0.f, 0.f, 0.f}, c1 = {0.f, 0.f, 0.f, 0.f};
    AMfma<0>::run(cur, fragL, c0, c1);

    // Epilogue: C row (g*4+i)=e_local; delta[r][e] is byte (EB&1)*4+i of fragL[EB>>1].
    constexpr int kk = EB >> 1;
    int src = (int)(fragL[kk] >> ((EB & 1) * 32));
    f32x2 f01 = __builtin_amdgcn_cvt_pk_f32_fp8(src, false);
    f32x2 f23 = __builtin_amdgcn_cvt_pk_f32_fp8(src, true);
    part += (c0[0] + c1[0]) * f01[0] + (c0[1] + c1[1]) * f01[1]
          + (c0[2] + c1[2]) * f23[0] + (c0[3] + c1[3]) * f23[1];

    ChunkLoop<EB + 1>::run(wsb, rot, fragL, nxt, cur, part);
  }
};
template <>
struct ChunkLoop<N_CHUNKS> {
  static __device__ __forceinline__ void run(const char*, int,
                                             const long long (&)[16],
                                             i32x4 (&)[8], i32x4 (&)[8], float&) {}
};

// out[row] = fp32 sumsq(delta) + (1/64) * delta^T (64R) delta  via fp8 MFMA.
// One wave per block, fully independent: no LDS, no __syncthreads, R streamed
// from L2 (256 KB, resident). launch_bounds(64,3) caps VGPR at ~170 (est. need
// ~140: fragL 32 + A/B 64 + acc 8 + addr/temps) — 3 waves/SIMD, 12/CU.
__global__ __launch_bounds__(64, 3)
void mahal_main(const float* __restrict__ X, const float* __restrict__ XF,
                const uint32_t* __restrict__ ws, float* __restrict__ out) {
  const int lane = threadIdx.x;
  const int m    = lane & 15;          // delta row within wave
  const int g    = lane >> 4;          // lane group
  const int row  = blockIdx.x * ROWS_PER_BLOCK + m;

  const float* xr = X  + (size_t)row * DIM;
  const float* fr = XF + (size_t)row * DIM;

  long long fragL[16];
  float sumsq = 0.f;
  P0<0>::run(xr, fr, g, fragL, sumsq);
  sumsq += __shfl_xor(sumsq, 16);
  sumsq += __shfl_xor(sumsq, 32);

  const char* wsb = (const char*)ws + m * 512;   // per-lane chunk-row base
  const int rot = g + m;                          // atom-slot rotation

  i32x4 A[8], B[8];
  ALoad<0>::run(wsb, rot, A);                     // chunk 0 into flight

  float part = 0.f;
  ChunkLoop<0>::run(wsb, rot, fragL, A, B, part);

  part += __shfl_xor(part, 16);
  part += __shfl_xor(part, 32);
  if (g == 0) out[row] = sumsq + part * 0.015625f;   // 1/64 undoes R scaling
}

// Safety-net (only if ws_size is unexpectedly small): naive fp32, correct.
__global__ void mahal_naive(const float* __restrict__ X, const float* __restrict__ XF,
                            const float* __restrict__ S, float* __restrict__ out, int n) {
  int row = blockIdx.x * blockDim.x + threadIdx.x;
  if (row >= n) return;
  const float* xr = X + (size_t)row * DIM;
  const float* fr = XF + (size_t)row * DIM;
  float acc = 0.f;
  for (int d = 0; d < DIM; ++d) {
    float dd = xr[d] - fr[d];
    float inner = 0.f;
    for (int e = 0; e < DIM; ++e) inner += S[d * DIM + e] * (xr[e] - fr[e]);
    acc += dd * inner;
  }
  out[row] = acc;
}

extern "C" void kernel_launch(void* const* d_in, const int* in_sizes, int n_in,
                              void* d_out, int out_size, void* d_ws, size_t ws_size,
                              hipStream_t stream) {
  const float* X  = (const float*)d_in[0];
  const float* XF = (const float*)d_in[1];
  const float* S  = (const float*)d_in[2];
  float* out = (float*)d_out;
  const int N = in_sizes[0] / DIM;

  if (ws_size < (size_t)WS_BYTES || (N % ROWS_PER_BLOCK) != 0) {
    mahal_naive<<<(N + 63) / 64, 64, 0, stream>>>(X, XF, S, out, N);
    return;
  }

  uint32_t* ws = (uint32_t*)d_ws;
  prep_R<<<(WS_BYTES / 4 + 255) / 256, 256, 0, stream>>>(S, ws);
  mahal_main<<<N / ROWS_PER_BLOCK, 64, 0, stream>>>(X, XF, ws, out);
}

// Round 2
// 332.579 us; speedup vs baseline: 1.1701x; 1.1701x over previous
//
#include <hip/hip_runtime.h>
#include <stdint.h>

#define DIM 512
#define ROWS_PER_BLOCK 16                // one wave, 16 rows
#define N_CHUNKS 32                      // 32 chunks of 16 e-columns
#define CHUNK_BYTES 8192                 // 16 rows x 512 fp8 (atom-rotated, no pad)
#define WS_BYTES (N_CHUNKS * CHUNK_BYTES)   // 262144

typedef __attribute__((ext_vector_type(4))) float f32x4;
typedef __attribute__((ext_vector_type(2))) float f32x2;
typedef __attribute__((ext_vector_type(4))) int   i32x4;

// k-permutation (validated rounds 1-3): position q = g*8+j within 32-k block kk
// holds k = 32*kk + (j<4 ? 4g+j : 16+4g+(j-4)). Any A/B-consistent bijection is
// mathematically valid; this one puts epilogue value delta[r][e] in-lane:
// e = 16*eb + 4g + i  <->  frag[eb>>1], byte (eb&1)*4 + i.
static __device__ __forceinline__ int kperm(int kk, int q) {
  int g = q >> 3, j = q & 7;
  int r = (j < 4) ? (g * 4 + j) : (16 + g * 4 + (j - 4));
  return kk * 32 + r;
}

// Build fp8 image of 64*(S - I), pre-swizzled: chunk -> 16 rows (e_l) x 512 B.
// Within a row, 16B atom (P,g) [atom index 4P+g] is stored at physical slot
// ((4P+g)+e_l)&31. (Rotation was for LDS banks; harmless for L2 reads, and the
// layout is validated — kept byte-identical.)
__global__ void prep_R(const float* __restrict__ S, uint32_t* __restrict__ ws) {
  int idx = blockIdx.x * blockDim.x + threadIdx.x;   // word index
  if (idx >= WS_BYTES / 4) return;
  int b     = idx * 4;
  int chunk = b >> 13;
  int e_l   = (b >> 9) & 15;
  int inrow = b & 511;
  int slot  = inrow >> 4;
  int bia   = inrow & 15;                // byte-in-atom base (0,4,8,12)
  int la    = (slot - e_l) & 31;         // logical atom = 4P+g
  int P = la >> 2, g = la & 3;
  int e = chunk * 16 + e_l;
  float v[4];
#pragma unroll
  for (int t = 0; t < 4; ++t) {
    int bb = bia + t;                    // byte in atom 0..15
    int j  = bb & 7;
    int kk = 2 * P + (bb >> 3);
    int k  = kperm(kk, g * 8 + j);
    v[t] = 64.0f * (S[k * DIM + e] - (k == e ? 1.0f : 0.0f));   // x64: e4m3 range
  }
  int w = __builtin_amdgcn_cvt_pk_fp8_f32(v[0], v[1], 0, false);
  w     = __builtin_amdgcn_cvt_pk_fp8_f32(v[2], v[3], w, true);
  ws[idx] = (uint32_t)w;
}

// ---- Phase 0 (template-unrolled, constant frag indices) ----
template <int KK>
struct P0 {
  static __device__ __forceinline__ void run(const float* __restrict__ xr,
                                             const float* __restrict__ fr,
                                             int g, long long (&fragL)[16], float& sumsq) {
    const float4 a0 = *(const float4*)(xr + KK * 32 + 4 * g);
    const float4 b0 = *(const float4*)(fr + KK * 32 + 4 * g);
    const float4 a1 = *(const float4*)(xr + KK * 32 + 16 + 4 * g);
    const float4 b1 = *(const float4*)(fr + KK * 32 + 16 + 4 * g);
    float d0 = a0.x - b0.x, d1 = a0.y - b0.y, d2 = a0.z - b0.z, d3 = a0.w - b0.w;
    float d4 = a1.x - b1.x, d5 = a1.y - b1.y, d6 = a1.z - b1.z, d7 = a1.w - b1.w;
    sumsq += d0*d0 + d1*d1 + d2*d2 + d3*d3 + d4*d4 + d5*d5 + d6*d6 + d7*d7;
    int lo = __builtin_amdgcn_cvt_pk_fp8_f32(d0, d1, 0, false);
    lo     = __builtin_amdgcn_cvt_pk_fp8_f32(d2, d3, lo, true);
    int hi = __builtin_amdgcn_cvt_pk_fp8_f32(d4, d5, 0, false);
    hi     = __builtin_amdgcn_cvt_pk_fp8_f32(d6, d7, hi, true);
    fragL[KK] = (long long)(((unsigned long long)(unsigned)hi << 32) | (unsigned)lo);
    P0<KK + 1>::run(xr, fr, g, fragL, sumsq);
  }
};
template <>
struct P0<16> {
  static __device__ __forceinline__ void run(const float*, const float*, int,
                                             long long (&)[16], float&) {}
};

// ---- Load one chunk's 8 A-atoms (16B each) straight from L2 into registers.
// Lane (m,g) reads chunk_base + m*512 + ((4P+g+m)&31)*16 — identical bytes to
// the old LDS image. Per instruction: 16 rows x 64B contiguous segments. ----
template <int P>
struct ALoad {
  static __device__ __forceinline__ void run(const char* __restrict__ cbase,
                                             int rot, i32x4 (&A)[8]) {
    int off = ((4 * P + rot) & 31) * 16;   // rotated atom slot
    A[P] = *(const i32x4*)(cbase + off);
    ALoad<P + 1>::run(cbase, rot, A);
  }
};
template <>
struct ALoad<8> {
  static __device__ __forceinline__ void run(const char*, int, i32x4 (&)[8]) {}
};

// ---- 8 atom-steps; each 16B register pair feeds two fp8 MFMAs ----
template <int P>
struct AMfma {
  static __device__ __forceinline__ void run(const i32x4 (&A)[8],
                                             const long long (&fragL)[16],
                                             f32x4& c0, f32x4& c1) {
    long long A0 = (long long)(((unsigned long long)(unsigned)A[P][1] << 32) | (unsigned)A[P][0]);
    long long A1 = (long long)(((unsigned long long)(unsigned)A[P][3] << 32) | (unsigned)A[P][2]);
    c0 = __builtin_amdgcn_mfma_f32_16x16x32_fp8_fp8(A0, fragL[2 * P],     c0, 0, 0, 0);
    c1 = __builtin_amdgcn_mfma_f32_16x16x32_fp8_fp8(A1, fragL[2 * P + 1], c1, 0, 0, 0);
    AMfma<P + 1>::run(A, fragL, c0, c1);
  }
};
template <>
struct AMfma<8> {
  static __device__ __forceinline__ void run(const i32x4 (&)[8],
                                             const long long (&)[16], f32x4&, f32x4&) {}
};

// ---- Chunk loop: register double-buffer, one chunk prefetched ahead.
// No LDS, no barriers — compiler emits counted vmcnt waits (8 loads of the
// next chunk stay in flight across each chunk's 16 MFMAs). cur/nxt swap via
// argument order, so every array index is compile-time (no scratch). ----
template <int EB>
struct ChunkLoop {
  static __device__ __forceinline__ void run(const char* __restrict__ wsb,
                                             int rot,
                                             const long long (&fragL)[16],
                                             i32x4 (&cur)[8], i32x4 (&nxt)[8],
                                             float& part) {
    if constexpr (EB + 1 < N_CHUNKS)
      ALoad<0>::run(wsb + (size_t)(EB + 1) * CHUNK_BYTES, rot, nxt);

    f32x4 c0 = {0.f, 0.f, 0.f, 0.f}, c1 = {0.f, 0.f, 0.f, 0.f};
    AMfma<0>::run(cur, fragL, c0, c1);

    // Epilogue: C row (g*4+i)=e_local; delta[r][e] is byte (EB&1)*4+i of fragL[EB>>1].
    constexpr int kk = EB >> 1;
    int src = (int)(fragL[kk] >> ((EB & 1) * 32));
    f32x2 f01 = __builtin_amdgcn_cvt_pk_f32_fp8(src, false);
    f32x2 f23 = __builtin_amdgcn_cvt_pk_f32_fp8(src, true);
    part += (c0[0] + c1[0]) * f01[0] + (c0[1] + c1[1]) * f01[1]
          + (c0[2] + c1[2]) * f23[0] + (c0[3] + c1[3]) * f23[1];

    ChunkLoop<EB + 1>::run(wsb, rot, fragL, nxt, cur, part);
  }
};
template <>
struct ChunkLoop<N_CHUNKS> {
  static __device__ __forceinline__ void run(const char*, int,
                                             const long long (&)[16],
                                             i32x4 (&)[8], i32x4 (&)[8], float&) {}
};

// out[row] = fp32 sumsq(delta) + (1/64) * delta^T (64R) delta  via fp8 MFMA.
// One wave per block, fully independent: no LDS, no __syncthreads, R streamed
// from L2 (256 KB, resident).
// launch_bounds(64,2): 256 VGPR/wave -> allocator's 50:50 arch/acc split gives
// 128 arch + 128 acc. Arch need: fragL 32 + cur 32 + nxt 32 + ~20 addr = ~116.
// (Round-1 lesson: (64,3) -> 168 total -> 84 arch -> 96-reg data set spilled,
// 162 MB scratch writes. VGPR_Count=84 was the tell.)
__global__ __launch_bounds__(64, 2)
void mahal_main(const float* __restrict__ X, const float* __restrict__ XF,
                const uint32_t* __restrict__ ws, float* __restrict__ out) {
  const int lane = threadIdx.x;
  const int m    = lane & 15;          // delta row within wave
  const int g    = lane >> 4;          // lane group
  const int row  = blockIdx.x * ROWS_PER_BLOCK + m;

  const float* xr = X  + (size_t)row * DIM;
  const float* fr = XF + (size_t)row * DIM;

  const char* wsb = (const char*)ws + m * 512;   // per-lane chunk-row base
  const int rot = g + m;                          // atom-slot rotation

  // Issue chunk-0 L2 reads first: they fly during P0's HBM-bound phase.
  i32x4 A[8], B[8];
  ALoad<0>::run(wsb, rot, A);

  long long fragL[16];
  float sumsq = 0.f;
  P0<0>::run(xr, fr, g, fragL, sumsq);
  sumsq += __shfl_xor(sumsq, 16);
  sumsq += __shfl_xor(sumsq, 32);

  float part = 0.f;
  ChunkLoop<0>::run(wsb, rot, fragL, A, B, part);

  part += __shfl_xor(part, 16);
  part += __shfl_xor(part, 32);
  if (g == 0) out[row] = sumsq + part * 0.015625f;   // 1/64 undoes R scaling
}

// Safety-net (only if ws_size is unexpectedly small): naive fp32, correct.
__global__ void mahal_naive(const float* __restrict__ X, const float* __restrict__ XF,
                            const float* __restrict__ S, float* __restrict__ out, int n) {
  int row = blockIdx.x * blockDim.x + threadIdx.x;
  if (row >= n) return;
  const float* xr = X + (size_t)row * DIM;
  const float* fr = XF + (size_t)row * DIM;
  float acc = 0.f;
  for (int d = 0; d < DIM; ++d) {
    float dd = xr[d] - fr[d];
    float inner = 0.f;
    for (int e = 0; e < DIM; ++e) inner += S[d * DIM + e] * (xr[e] - fr[e]);
    acc += dd * inner;
  }
  out[row] = acc;
}

extern "C" void kernel_launch(void* const* d_in, const int* in_sizes, int n_in,
                              void* d_out, int out_size, void* d_ws, size_t ws_size,
                              hipStream_t stream) {
  const float* X  = (const float*)d_in[0];
  const float* XF = (const float*)d_in[1];
  const float* S  = (const float*)d_in[2];
  float* out = (float*)d_out;
  const int N = in_sizes[0] / DIM;

  if (ws_size < (size_t)WS_BYTES || (N % ROWS_PER_BLOCK) != 0) {
    mahal_naive<<<(N + 63) / 64, 64, 0, stream>>>(X, XF, S, out, N);
    return;
  }

  uint32_t* ws = (uint32_t*)d_ws;
  prep_R<<<(WS_BYTES / 4 + 255) / 256, 256, 0, stream>>>(S, ws);
  mahal_main<<<N / ROWS_PER_BLOCK, 64, 0, stream>>>(X, XF, ws, out);
}

// Round 3
// 304.713 us; speedup vs baseline: 1.2771x; 1.0914x over previous
//
#include <hip/hip_runtime.h>
#include <stdint.h>

#define DIM 512
#define ROWS_PER_BLOCK 64                // 4 waves x 16 rows
#define N_CHUNKS 32                      // 32 chunks of 16 e-columns
#define CHUNK_BYTES 8192                 // 16 rows x 512 fp8 (atom-rotated, no pad)
#define WS_BYTES (N_CHUNKS * CHUNK_BYTES)   // 262144
#define N_BUF 4                          // LDS ring buffers (32 KB total)
#define PREFETCH 3                       // stage depth: chunk EB+3 in flight

typedef __attribute__((ext_vector_type(4))) float f32x4;
typedef __attribute__((ext_vector_type(2))) float f32x2;
typedef __attribute__((ext_vector_type(4))) int   i32x4;

// k-permutation (validated): position q = g*8+j within 32-k block kk holds
// k = 32*kk + (j<4 ? 4g+j : 16+4g+(j-4)). Puts epilogue value delta[r][e]
// in-lane: e = 16*eb + 4g + i  <->  frag[eb>>1], byte (eb&1)*4 + i.
static __device__ __forceinline__ int kperm(int kk, int q) {
  int g = q >> 3, j = q & 7;
  int r = (j < 4) ? (g * 4 + j) : (16 + g * 4 + (j - 4));
  return kk * 32 + r;
}

// Build fp8 image of 64*(S - I), pre-swizzled: chunk -> 16 rows (e_l) x 512 B.
// Within a row, 16B atom (P,g) [atom index 4P+g] is stored at physical slot
// ((4P+g)+e_l)&31 — per-row rotation spreads the K-loop's b128 reads over banks.
__global__ void prep_R(const float* __restrict__ S, uint32_t* __restrict__ ws) {
  int idx = blockIdx.x * blockDim.x + threadIdx.x;   // word index
  if (idx >= WS_BYTES / 4) return;
  int b     = idx * 4;
  int chunk = b >> 13;
  int e_l   = (b >> 9) & 15;
  int inrow = b & 511;
  int slot  = inrow >> 4;
  int bia   = inrow & 15;                // byte-in-atom base (0,4,8,12)
  int la    = (slot - e_l) & 31;         // logical atom = 4P+g
  int P = la >> 2, g = la & 3;
  int e = chunk * 16 + e_l;
  float v[4];
#pragma unroll
  for (int t = 0; t < 4; ++t) {
    int bb = bia + t;                    // byte in atom 0..15
    int j  = bb & 7;
    int kk = 2 * P + (bb >> 3);
    int k  = kperm(kk, g * 8 + j);
    v[t] = 64.0f * (S[k * DIM + e] - (k == e ? 1.0f : 0.0f));   // x64: e4m3 range
  }
  int w = __builtin_amdgcn_cvt_pk_fp8_f32(v[0], v[1], 0, false);
  w     = __builtin_amdgcn_cvt_pk_fp8_f32(v[2], v[3], w, true);
  ws[idx] = (uint32_t)w;
}

// Stage one 8 KB R-chunk into LDS (async direct-to-LDS, width 16, linear).
static __device__ __forceinline__ void stage_chunk(const uint32_t* __restrict__ ws,
                                                   int eb, char* dst, int tid) {
  const uint32_t* src = ws + (size_t)eb * (CHUNK_BYTES / 4);
#pragma unroll
  for (int r = 0; r < 2; ++r) {                      // 512 x 16B slots
    int idx = r * 256 + tid;
    __builtin_amdgcn_global_load_lds(
        (const __attribute__((address_space(1))) void*)(src + idx * 4),
        (__attribute__((address_space(3))) void*)(dst + idx * 16),
        16, 0, 0);
  }
}

// ---- Phase 0 (template-unrolled, constant frag indices) ----
template <int KK>
struct P0 {
  static __device__ __forceinline__ void run(const float* __restrict__ xr,
                                             const float* __restrict__ fr,
                                             int g, long long (&fragL)[16], float& sumsq) {
    const float4 a0 = *(const float4*)(xr + KK * 32 + 4 * g);
    const float4 b0 = *(const float4*)(fr + KK * 32 + 4 * g);
    const float4 a1 = *(const float4*)(xr + KK * 32 + 16 + 4 * g);
    const float4 b1 = *(const float4*)(fr + KK * 32 + 16 + 4 * g);
    float d0 = a0.x - b0.x, d1 = a0.y - b0.y, d2 = a0.z - b0.z, d3 = a0.w - b0.w;
    float d4 = a1.x - b1.x, d5 = a1.y - b1.y, d6 = a1.z - b1.z, d7 = a1.w - b1.w;
    sumsq += d0*d0 + d1*d1 + d2*d2 + d3*d3 + d4*d4 + d5*d5 + d6*d6 + d7*d7;
    int lo = __builtin_amdgcn_cvt_pk_fp8_f32(d0, d1, 0, false);
    lo     = __builtin_amdgcn_cvt_pk_fp8_f32(d2, d3, lo, true);
    int hi = __builtin_amdgcn_cvt_pk_fp8_f32(d4, d5, 0, false);
    hi     = __builtin_amdgcn_cvt_pk_fp8_f32(d6, d7, hi, true);
    fragL[KK] = (long long)(((unsigned long long)(unsigned)hi << 32) | (unsigned)lo);
    P0<KK + 1>::run(xr, fr, g, fragL, sumsq);
  }
};
template <>
struct P0<16> {
  static __device__ __forceinline__ void run(const float*, const float*, int,
                                             long long (&)[16], float&) {}
};

// ---- K-loop over 8 atom-steps; each b128 feeds two fp8 MFMAs ----
template <int P>
struct KLoop {
  static __device__ __forceinline__ void run(const char* __restrict__ rowbase,
                                             int g, int m,
                                             const long long (&fragL)[16],
                                             f32x4& c0, f32x4& c1) {
    int off = ((4 * P + g + m) & 31) * 16;           // rotated atom slot
    i32x4 a = *(const i32x4*)(rowbase + off);
    long long A0 = (long long)(((unsigned long long)(unsigned)a[1] << 32) | (unsigned)a[0]);
    long long A1 = (long long)(((unsigned long long)(unsigned)a[3] << 32) | (unsigned)a[2]);
    c0 = __builtin_amdgcn_mfma_f32_16x16x32_fp8_fp8(A0, fragL[2 * P],     c0, 0, 0, 0);
    c1 = __builtin_amdgcn_mfma_f32_16x16x32_fp8_fp8(A1, fragL[2 * P + 1], c1, 0, 0, 0);
    KLoop<P + 1>::run(rowbase, g, m, fragL, c0, c1);
  }
};
template <>
struct KLoop<8> {
  static __device__ __forceinline__ void run(const char*, int, int,
                                             const long long (&)[16], f32x4&, f32x4&) {}
};

// ---- Chunk loop: 4-buffer LDS ring, depth-3 prefetch, ONE raw s_barrier per
// chunk with counted vmcnt (T3+T4). Never vmcnt(0) in steady state — the
// __syncthreads full-drain was the round-0 kernel's ~2/3 overhead.
// Hazards: compute(EB) reads buf[EB&3]; in-flight stages EB+1..EB+3 target the
// other 3 buffers (disjoint). stage(EB+3), issued after the barrier, overwrites
// buf[(EB-1)&3] — every wave passed this barrier only after finishing chunk
// EB-1's ds_reads (lgkmcnt(0) folded into the same waitcnt). ----
template <int EB>
struct ChunkLoop {
  static __device__ __forceinline__ void run(const uint32_t* __restrict__ ws,
                                             char* __restrict__ sbase,
                                             int tid, int m, int g,
                                             const long long (&fragL)[16], float& part) {
    // Wait: stage EB complete. Outstanding per wave after the wait:
    // stages EB+1, EB+2 (2 loads each). Epilogue chunks drain 2 -> 0.
    if constexpr (EB <= N_CHUNKS - 3)
      asm volatile("s_waitcnt vmcnt(4) lgkmcnt(0)" ::: "memory");
    else if constexpr (EB == N_CHUNKS - 2)
      asm volatile("s_waitcnt vmcnt(2) lgkmcnt(0)" ::: "memory");
    else
      asm volatile("s_waitcnt vmcnt(0) lgkmcnt(0)" ::: "memory");
    __builtin_amdgcn_s_barrier();

    if constexpr (EB + PREFETCH < N_CHUNKS)
      stage_chunk(ws, EB + PREFETCH,
                  sbase + ((EB + PREFETCH) & (N_BUF - 1)) * CHUNK_BYTES, tid);

    const char* rowbase = sbase + (EB & (N_BUF - 1)) * CHUNK_BYTES + m * 512;
    f32x4 c0 = {0.f, 0.f, 0.f, 0.f}, c1 = {0.f, 0.f, 0.f, 0.f};
    KLoop<0>::run(rowbase, g, m, fragL, c0, c1);

    // Epilogue: C row (g*4+i)=e_local; delta[r][e] is byte (EB&1)*4+i of fragL[EB>>1].
    constexpr int kk = EB >> 1;
    int src = (int)(fragL[kk] >> ((EB & 1) * 32));
    f32x2 f01 = __builtin_amdgcn_cvt_pk_f32_fp8(src, false);
    f32x2 f23 = __builtin_amdgcn_cvt_pk_f32_fp8(src, true);
    part += (c0[0] + c1[0]) * f01[0] + (c0[1] + c1[1]) * f01[1]
          + (c0[2] + c1[2]) * f23[0] + (c0[3] + c1[3]) * f23[1];

    ChunkLoop<EB + 1>::run(ws, sbase, tid, m, g, fragL, part);
  }
};
template <>
struct ChunkLoop<N_CHUNKS> {
  static __device__ __forceinline__ void run(const uint32_t*, char*, int, int, int,
                                             const long long (&)[16], float&) {}
};

// out[row] = fp32 sumsq(delta) + (1/64) * delta^T (64R) delta  via fp8 MFMA.
// 4-wave blocks (R read amortized 4x vs 1-wave: rounds 1-2 showed the register
// pipeline is L2-latency-bound and spills — VGPR budget can't hold 96+ data
// regs). fp8 frag = 32 VGPRs fits the allocator's 50:50 arch/acc split at
// launch_bounds(256,2) (VGPR_Count 100, no spill — round-0 verified).
__global__ __launch_bounds__(256, 2)
void mahal_main(const float* __restrict__ X, const float* __restrict__ XF,
                const uint32_t* __restrict__ ws, float* __restrict__ out) {
  __shared__ __align__(16) char sA[N_BUF][CHUNK_BYTES];   // 32 KB

  const int tid  = threadIdx.x;
  const int lane = tid & 63;
  const int wv   = tid >> 6;
  const int m    = lane & 15;          // delta row within wave
  const int g    = lane >> 4;          // lane group
  const int row  = blockIdx.x * ROWS_PER_BLOCK + wv * 16 + m;

  const float* xr = X  + (size_t)row * DIM;
  const float* fr = XF + (size_t)row * DIM;

  // Prologue: put 3 chunks in flight; their L2 latency hides under P0's
  // HBM-bound delta computation.
  stage_chunk(ws, 0, sA[0], tid);
  stage_chunk(ws, 1, sA[1], tid);
  stage_chunk(ws, 2, sA[2], tid);

  long long fragL[16];
  float sumsq = 0.f;
  P0<0>::run(xr, fr, g, fragL, sumsq);
  sumsq += __shfl_xor(sumsq, 16);
  sumsq += __shfl_xor(sumsq, 32);

  float part = 0.f;
  ChunkLoop<0>::run(ws, &sA[0][0], tid, m, g, fragL, part);

  part += __shfl_xor(part, 16);
  part += __shfl_xor(part, 32);
  if (g == 0) out[row] = sumsq + part * 0.015625f;   // 1/64 undoes R scaling
}

// Safety-net (only if ws_size is unexpectedly small): naive fp32, correct.
__global__ void mahal_naive(const float* __restrict__ X, const float* __restrict__ XF,
                            const float* __restrict__ S, float* __restrict__ out, int n) {
  int row = blockIdx.x * blockDim.x + threadIdx.x;
  if (row >= n) return;
  const float* xr = X + (size_t)row * DIM;
  const float* fr = XF + (size_t)row * DIM;
  float acc = 0.f;
  for (int d = 0; d < DIM; ++d) {
    float dd = xr[d] - fr[d];
    float inner = 0.f;
    for (int e = 0; e < DIM; ++e) inner += S[d * DIM + e] * (xr[e] - fr[e]);
    acc += dd * inner;
  }
  out[row] = acc;
}

extern "C" void kernel_launch(void* const* d_in, const int* in_sizes, int n_in,
                              void* d_out, int out_size, void* d_ws, size_t ws_size,
                              hipStream_t stream) {
  const float* X  = (const float*)d_in[0];
  const float* XF = (const float*)d_in[1];
  const float* S  = (const float*)d_in[2];
  float* out = (float*)d_out;
  const int N = in_sizes[0] / DIM;

  if (ws_size < (size_t)WS_BYTES || (N % ROWS_PER_BLOCK) != 0) {
    mahal_naive<<<(N + 63) / 64, 64, 0, stream>>>(X, XF, S, out, N);
    return;
  }

  uint32_t* ws = (uint32_t*)d_ws;
  prep_R<<<(WS_BYTES / 4 + 255) / 256, 256, 0, stream>>>(S, ws);
  mahal_main<<<N / ROWS_PER_BLOCK, 256, 0, stream>>>(X, XF, ws, out);
}